// Round 5
// baseline (287.591 us; speedup 1.0000x reference)
//
#include <hip/hip_runtime.h>

// One row per thread, 1 wave/SIMD (launch_bounds(256,1)), ALL 320 MLP weight
// scalars pinned in VGPRs via an opaque asm keepalive so the allocator
// cannot rematerialize the LDS reads into the t-loop (round-4 failure:
// VGPR_Count=212 proved it remat'd, keeping the per-CU LDS pipe saturated
// at ~115us). With weights resident, the k-loop is pure-VGPR FMA and the
// only in-loop LDS traffic is 10 record ds_writes/step.
// I/O structure unchanged from the verified round-1/3 kernel.

constexpr int kB     = 262144;
constexpr int kSteps = 15;
constexpr int PAD    = 33;
constexpr int WOFF   = 256 * PAD;      // weight staging region (16B aligned)

__device__ __forceinline__ float relu_(float v) { return fmaxf(v, 0.0f); }
__device__ __forceinline__ float sigmoid_(float v) {
    return __builtin_amdgcn_rcpf(1.0f + __expf(-v));
}

__global__ __launch_bounds__(256, 1) void Program_4578435138231_kernel(
    const float* __restrict__ x,
    const float* __restrict__ c1w, const float* __restrict__ c1b,
    const float* __restrict__ c2w, const float* __restrict__ c2b,
    const float* __restrict__ l1w, const float* __restrict__ l1b,
    const float* __restrict__ l2w, const float* __restrict__ l2b,
    float* __restrict__ out)
{
    __shared__ __align__(16) float lds[256 * PAD + 32 * 12];   // 35.3 KB
    const int tid = threadIdx.x;
    const int R0  = blockIdx.x * 256;  // grid exactly covers kB: no tail

    // ---- stage packed weights: [k][ w1c0 w1c1 w1c2 w1c3 b1 w2j0..4 pad pad ]
    if (tid < 32) {
        const int k = tid;
        float* w = lds + WOFF + k * 12;
        w[0] = l1w[k];          w[1] = l1w[32 + k];
        w[2] = l1w[64 + k];     w[3] = l1w[96 + k];
        w[4] = l1b[k];
        w[5] = l2w[5 * k + 0];  w[6] = l2w[5 * k + 1];
        w[7] = l2w[5 * k + 2];  w[8] = l2w[5 * k + 3];
        w[9] = l2w[5 * k + 4];
    }

    // ---- coalesced input stage: block tile 256 rows x 18 cols ----
    {
        const float* xblk = x + (size_t)R0 * 18;
        #pragma unroll
        for (int j = 0; j < 18; ++j) {
            int flat = tid + 256 * j;                          // 0..4607
            float v  = xblk[flat];                             // lane-contiguous
            int r = (int)(((unsigned)flat * 58255u) >> 20);    // flat / 18
            int c = flat - r * 18;
            lds[r * PAD + c] = v;
        }
    }
    __syncthreads();
    float s[18];
    #pragma unroll
    for (int j = 0; j < 18; ++j) s[j] = lds[tid * PAD + j];

    // ---- pull ALL weights into registers, then PIN them (opaque asm) ----
    const float* wl = lds + WOFF;
    float wA[32], wB[32], wC[32], wD[32], wE[32];   // l1w cols 0..3, l1b
    float wF[32], wG[32], wH[32], wI[32], wJ[32];   // l2w j=0..4
    #pragma unroll
    for (int k = 0; k < 32; ++k) {
        float4 a = *reinterpret_cast<const float4*>(wl + k * 12);
        float4 b = *reinterpret_cast<const float4*>(wl + k * 12 + 4);
        float2 c = *reinterpret_cast<const float2*>(wl + k * 12 + 8);
        wA[k] = a.x; wB[k] = a.y; wC[k] = a.z; wD[k] = a.w; wE[k] = b.x;
        wF[k] = b.y; wG[k] = b.z; wH[k] = b.w; wI[k] = c.x; wJ[k] = c.y;
    }
    #pragma unroll
    for (int k = 0; k < 32; ++k) {
        asm volatile("" : "+v"(wA[k]), "+v"(wB[k]), "+v"(wC[k]), "+v"(wD[k]),
                          "+v"(wE[k]), "+v"(wF[k]), "+v"(wG[k]), "+v"(wH[k]),
                          "+v"(wI[k]), "+v"(wJ[k]));
    }
    __syncthreads();   // window region (incl. weight staging) now reusable

    const float cw10 = c1w[0], cw11 = c1w[1], cb1 = c1b[0];
    const float cw20 = c2w[0], cw21 = c2w[1], cb2 = c2b[0];
    const float b20 = l2b[0], b21 = l2b[1], b22 = l2b[2], b23 = l2b[3], b24 = l2b[4];

    // s[10] = distance
    {
        float dA = s[1] - s[3], dB = s[2] - s[4];
        s[10] = dA * dA + dB * dB;
    }

    float* lr = lds + tid * PAD;

    // flush current 256x32 window (cols [wcol, wcol+32)) coalesced
    auto flush32 = [&](int wcol) {
        __syncthreads();
        const int rr = tid >> 5, cc = tid & 31;
        const float* lp = lds + rr * PAD + cc;
        float*       op = out + (size_t)(R0 + rr) * 178 + wcol + cc;
        #pragma unroll
        for (int j = 0; j < 32; ++j) {
            op[(size_t)(8 * j) * 178] = lp[8 * j * PAD];
        }
        __syncthreads();
    };

    int wstart = 18;   // first output col held at LDS idx 0
    int nextb  = 50;   // next window boundary col

    // traj0 = s[TRAJ_IDX] at cols 18..27 -> idx 0..9
    lr[0] = s[10]; lr[1] = s[1];  lr[2] = s[2]; lr[3] = s[3]; lr[4] = s[4];
    lr[5] = s[5];  lr[6] = s[6];  lr[7] = s[7]; lr[8] = s[8]; lr[9] = s[17];

    #pragma unroll 1
    for (int t = 0; t < kSteps; ++t) {
        // ---- classifier on feat = s[[1,2,3,4,9,17]] ----
        float f0 = s[1], f1 = s[2], f2 = s[3], f3 = s[4], f4 = s[9], f5 = s[17];
        float h10 = relu_(cw10 * f0 + cw11 * f1 + cb1);
        float h11 = relu_(cw10 * f1 + cw11 * f2 + cb1);
        float h12 = relu_(cw10 * f2 + cw11 * f3 + cb1);
        float h13 = relu_(cw10 * f3 + cw11 * f4 + cb1);
        float h14 = relu_(cw10 * f4 + cw11 * f5 + cb1);
        float g0 = relu_(cw20 * h10 + cw21 * h11 + cb2);
        float g1 = relu_(cw20 * h11 + cw21 * h12 + cb2);
        float g2 = relu_(cw20 * h12 + cw21 * h13 + cb2);
        float g3 = relu_(cw20 * h13 + cw21 * h14 + cb2);

        float p0 = b20, p1 = b21, p2 = b22, p3 = b23, p4 = b24;
        #pragma unroll
        for (int k = 0; k < 32; ++k) {
            float h = g0 * wA[k] + g1 * wB[k] + g2 * wC[k]
                    + g3 * wD[k] + wE[k];
            h = relu_(h);
            p0 += h * wF[k];
            p1 += h * wG[k];
            p2 += h * wH[k];
            p3 += h * wI[k];
            p4 += h * wJ[k];
        }
        p0 = sigmoid_(p0); p1 = sigmoid_(p1); p2 = sigmoid_(p2);
        p3 = sigmoid_(p3); p4 = sigmoid_(p4);

        s[5] = p0; s[6] = p1; s[7] = p2; s[8] = p3; s[17] = p4;
        float a = p1 - p0, b = p2 - p0, c = p3 - p0;
        float d = p2 - p1, e = p3 - p1, f = p3 - p2;
        s[11] = a; s[12] = b; s[13] = c; s[14] = d; s[15] = e; s[16] = f;

        float dx_c = (c <= 0.f) ? 0.f  : 5.f,  st_c = (c <= 0.f) ? 0.f : 3.f;
        float dx_f = (f <= 0.f) ? 0.f  : 5.f,  st_f = (f <= 0.f) ? 2.f : 3.f;
        float dx_e = (e <= 0.f) ? -5.f : 5.f,  st_e = (e <= 0.f) ? 1.f : 3.f;
        float dx_b = (b <= 0.f) ? dx_c : dx_f, st_b = (b <= 0.f) ? st_c : st_f;
        float dx_d = (d <= 0.f) ? dx_e : dx_f, st_d = (d <= 0.f) ? st_e : st_f;
        float dx   = (a <= 0.f) ? dx_b : dx_d, st   = (a <= 0.f) ? st_b : st_d;

        s[1] += dx; s[9] = st;
        s[2] += 5.f; s[3] += 5.f; s[0] += 1.f;
        float dA = s[1] - s[3], dB = s[2] - s[4];
        s[10] = dA * dA + dB * dB;

        // ---- record s[TRAJ_IDX] into the LDS window (cols c0..c0+9) ----
        float v0 = s[10], v1 = s[1], v2 = s[2], v3 = s[3], v4 = s[4];
        float v5 = s[5],  v6 = s[6], v7 = s[7], v8 = s[8], v9 = s[17];
        const int c0 = 28 + 10 * t;
        const int kk = nextb - c0;       // uniform split point
        int off = c0 - wstart;
        if (kk >= 10) {                  // record fits current window
            lr[off + 0] = v0; lr[off + 1] = v1; lr[off + 2] = v2;
            lr[off + 3] = v3; lr[off + 4] = v4; lr[off + 5] = v5;
            lr[off + 6] = v6; lr[off + 7] = v7; lr[off + 8] = v8;
            lr[off + 9] = v9;
            if (kk == 10) {              // window exactly full (t = 14)
                flush32(wstart);
                wstart = nextb; nextb += 32;
            }
        } else {                         // record straddles the boundary
            if (kk > 0) lr[off + 0] = v0;
            if (kk > 1) lr[off + 1] = v1;
            if (kk > 2) lr[off + 2] = v2;
            if (kk > 3) lr[off + 3] = v3;
            if (kk > 4) lr[off + 4] = v4;
            if (kk > 5) lr[off + 5] = v5;
            if (kk > 6) lr[off + 6] = v6;
            if (kk > 7) lr[off + 7] = v7;
            if (kk > 8) lr[off + 8] = v8;
            if (kk > 9) lr[off + 9] = v9;
            flush32(wstart);
            wstart = nextb; nextb += 32;
            off = c0 - wstart;           // negative; off+j >= 0 for j >= kk
            if (kk <= 0) lr[off + 0] = v0;
            if (kk <= 1) lr[off + 1] = v1;
            if (kk <= 2) lr[off + 2] = v2;
            if (kk <= 3) lr[off + 3] = v3;
            if (kk <= 4) lr[off + 4] = v4;
            if (kk <= 5) lr[off + 5] = v5;
            if (kk <= 6) lr[off + 6] = v6;
            if (kk <= 7) lr[off + 7] = v7;
            if (kk <= 8) lr[off + 8] = v8;
            if (kk <= 9) lr[off + 9] = v9;
        }
    }

    // ---- final state, cols 0..17, coalesced via LDS ----
    __syncthreads();
    #pragma unroll
    for (int j = 0; j < 18; ++j) lr[j] = s[j];
    __syncthreads();
    #pragma unroll
    for (int j = 0; j < 18; ++j) {
        int flat = tid + 256 * j;                          // 0..4607
        int r = (int)(((unsigned)flat * 58255u) >> 20);    // flat / 18
        int c = flat - r * 18;
        out[(size_t)(R0 + r) * 178 + c] = lds[r * PAD + c];
    }
}

extern "C" void kernel_launch(void* const* d_in, const int* in_sizes, int n_in,
                              void* d_out, int out_size, void* d_ws, size_t ws_size,
                              hipStream_t stream) {
    const float* x   = (const float*)d_in[0];
    const float* c1w = (const float*)d_in[1];
    const float* c1b = (const float*)d_in[2];
    const float* c2w = (const float*)d_in[3];
    const float* c2b = (const float*)d_in[4];
    const float* l1w = (const float*)d_in[5];
    const float* l1b = (const float*)d_in[6];
    const float* l2w = (const float*)d_in[7];
    const float* l2b = (const float*)d_in[8];
    float* out = (float*)d_out;

    Program_4578435138231_kernel<<<kB / 256, 256, 0, stream>>>(
        x, c1w, c1b, c2w, c2b, l1w, l1b, l2w, l2b, out);
}

// Round 6
// 269.097 us; speedup vs baseline: 1.0687x; 1.0687x over previous
//
#include <hip/hip_runtime.h>

// TWO LANES PER ROW: lane half=0 owns k=0..15, half=1 owns k=16..31 of the
// MLP hidden layer. Each thread keeps its 160 weight floats VGPR-resident
// (fits: ~210 VGPR < 256 cap, so the R5 spill failure mode is gone), loaded
// once before the t-loop. The k-loop is pure-VGPR FMA with ZERO memory ops;
// partials combine via __shfl_xor(.,1) (quad-perm DPP, pure VALU). Both
// lanes of a pair then carry identical state (A+B commutative -> bitwise
// same), so the serial t-loop stays lane-local.
// Rationale: R3/R4/R5 proved any per-step weight stream (ds_read, remat,
// or spill) costs ~100us regardless of occupancy; 320 floats/thread cannot
// be register-resident, so split the k-range across a lane pair.
// I/O chassis = verified round-1/3 window scheme at 128 rows/block.

constexpr int kB     = 262144;
constexpr int kSteps = 15;
constexpr int PAD    = 33;
constexpr int RPB    = 128;            // rows per block (2 lanes per row)
constexpr int WOFF   = RPB * PAD;      // weight staging region (16B aligned)

__device__ __forceinline__ float relu_(float v) { return fmaxf(v, 0.0f); }
__device__ __forceinline__ float sigmoid_(float v) {
    return __builtin_amdgcn_rcpf(1.0f + __expf(-v));
}

__global__ __launch_bounds__(256, 2) void Program_4578435138231_kernel(
    const float* __restrict__ x,
    const float* __restrict__ c1w, const float* __restrict__ c1b,
    const float* __restrict__ c2w, const float* __restrict__ c2b,
    const float* __restrict__ l1w, const float* __restrict__ l1b,
    const float* __restrict__ l2w, const float* __restrict__ l2b,
    float* __restrict__ out)
{
    __shared__ __align__(16) float lds[RPB * PAD + 32 * 12];   // 18.4 KB
    const int tid  = threadIdx.x;
    const int rid  = tid >> 1;          // local row 0..127
    const int half = tid & 1;           // k-range half
    const int R0   = blockIdx.x * RPB;  // grid exactly covers kB

    // ---- stage packed weights: [k][ w1c0 w1c1 w1c2 w1c3 b1 w2j0..4 pad pad ]
    if (tid < 32) {
        const int k = tid;
        float* w = lds + WOFF + k * 12;
        w[0] = l1w[k];          w[1] = l1w[32 + k];
        w[2] = l1w[64 + k];     w[3] = l1w[96 + k];
        w[4] = l1b[k];
        w[5] = l2w[5 * k + 0];  w[6] = l2w[5 * k + 1];
        w[7] = l2w[5 * k + 2];  w[8] = l2w[5 * k + 3];
        w[9] = l2w[5 * k + 4];
    }

    // ---- coalesced input stage: 128 rows x 18 cols = 2304 floats ----
    {
        const float* xblk = x + (size_t)R0 * 18;
        #pragma unroll
        for (int j = 0; j < 9; ++j) {
            int flat = tid + 256 * j;                          // 0..2303
            float v  = xblk[flat];
            int r = (int)(((unsigned)flat * 58255u) >> 20);    // flat / 18
            int c = flat - r * 18;
            lds[r * PAD + c] = v;
        }
    }
    __syncthreads();
    float s[18];
    #pragma unroll
    for (int j = 0; j < 18; ++j) s[j] = lds[rid * PAD + j];

    // ---- pull THIS HALF's 16 k-columns into registers, then pin them ----
    const float* wl = lds + WOFF + half * (16 * 12);
    float wA[16], wB[16], wC[16], wD[16], wE[16];   // l1w cols 0..3, l1b
    float wF[16], wG[16], wH[16], wI[16], wJ[16];   // l2w j=0..4
    #pragma unroll
    for (int k = 0; k < 16; ++k) {
        float4 a = *reinterpret_cast<const float4*>(wl + k * 12);
        float4 b = *reinterpret_cast<const float4*>(wl + k * 12 + 4);
        float2 c = *reinterpret_cast<const float2*>(wl + k * 12 + 8);
        wA[k] = a.x; wB[k] = a.y; wC[k] = a.z; wD[k] = a.w; wE[k] = b.x;
        wF[k] = b.y; wG[k] = b.z; wH[k] = b.w; wI[k] = c.x; wJ[k] = c.y;
    }
    #pragma unroll
    for (int k = 0; k < 16; ++k) {
        asm volatile("" : "+v"(wA[k]), "+v"(wB[k]), "+v"(wC[k]), "+v"(wD[k]),
                          "+v"(wE[k]), "+v"(wF[k]), "+v"(wG[k]), "+v"(wH[k]),
                          "+v"(wI[k]), "+v"(wJ[k]));
    }
    __syncthreads();   // window region (incl. weight staging) now reusable

    const float cw10 = c1w[0], cw11 = c1w[1], cb1 = c1b[0];
    const float cw20 = c2w[0], cw21 = c2w[1], cb2 = c2b[0];
    // bias lives only in half 0's partial; half 1 starts at 0
    const float b20 = half ? 0.f : l2b[0], b21 = half ? 0.f : l2b[1];
    const float b22 = half ? 0.f : l2b[2], b23 = half ? 0.f : l2b[3];
    const float b24 = half ? 0.f : l2b[4];

    // s[10] = distance
    {
        float dA = s[1] - s[3], dB = s[2] - s[4];
        s[10] = dA * dA + dB * dB;
    }

    float* lr = lds + rid * PAD;
    auto rec = [&](int idx, float v) { if (!half) lr[idx] = v; };

    // flush current 128x32 window (cols [wcol, wcol+32)) coalesced
    auto flush32 = [&](int wcol) {
        __syncthreads();
        const int rr = tid >> 5, cc = tid & 31;    // rr 0..7
        const float* lp = lds + rr * PAD + cc;
        float*       op = out + (size_t)(R0 + rr) * 178 + wcol + cc;
        #pragma unroll
        for (int j = 0; j < 16; ++j) {
            op[(size_t)(8 * j) * 178] = lp[8 * j * PAD];
        }
        __syncthreads();
    };

    int wstart = 18;   // first output col held at LDS idx 0
    int nextb  = 50;   // next window boundary col

    // traj0 = s[TRAJ_IDX] at cols 18..27 -> idx 0..9
    rec(0, s[10]); rec(1, s[1]);  rec(2, s[2]); rec(3, s[3]); rec(4, s[4]);
    rec(5, s[5]);  rec(6, s[6]);  rec(7, s[7]); rec(8, s[8]); rec(9, s[17]);

    #pragma unroll 1
    for (int t = 0; t < kSteps; ++t) {
        // ---- classifier on feat = s[[1,2,3,4,9,17]] ----
        float f0 = s[1], f1 = s[2], f2 = s[3], f3 = s[4], f4 = s[9], f5 = s[17];
        float h10 = relu_(cw10 * f0 + cw11 * f1 + cb1);
        float h11 = relu_(cw10 * f1 + cw11 * f2 + cb1);
        float h12 = relu_(cw10 * f2 + cw11 * f3 + cb1);
        float h13 = relu_(cw10 * f3 + cw11 * f4 + cb1);
        float h14 = relu_(cw10 * f4 + cw11 * f5 + cb1);
        float g0 = relu_(cw20 * h10 + cw21 * h11 + cb2);
        float g1 = relu_(cw20 * h11 + cw21 * h12 + cb2);
        float g2 = relu_(cw20 * h12 + cw21 * h13 + cb2);
        float g3 = relu_(cw20 * h13 + cw21 * h14 + cb2);

        // ---- this half's 16 k-columns, pure-VGPR ----
        float p0 = b20, p1 = b21, p2 = b22, p3 = b23, p4 = b24;
        #pragma unroll
        for (int k = 0; k < 16; ++k) {
            float h = g0 * wA[k] + g1 * wB[k] + g2 * wC[k]
                    + g3 * wD[k] + wE[k];
            h = relu_(h);
            p0 += h * wF[k];
            p1 += h * wG[k];
            p2 += h * wH[k];
            p3 += h * wI[k];
            p4 += h * wJ[k];
        }
        // combine lane-pair partials (quad-perm DPP, pure VALU)
        p0 += __shfl_xor(p0, 1, 64);
        p1 += __shfl_xor(p1, 1, 64);
        p2 += __shfl_xor(p2, 1, 64);
        p3 += __shfl_xor(p3, 1, 64);
        p4 += __shfl_xor(p4, 1, 64);

        p0 = sigmoid_(p0); p1 = sigmoid_(p1); p2 = sigmoid_(p2);
        p3 = sigmoid_(p3); p4 = sigmoid_(p4);

        s[5] = p0; s[6] = p1; s[7] = p2; s[8] = p3; s[17] = p4;
        float a = p1 - p0, b = p2 - p0, c = p3 - p0;
        float d = p2 - p1, e = p3 - p1, f = p3 - p2;
        s[11] = a; s[12] = b; s[13] = c; s[14] = d; s[15] = e; s[16] = f;

        float dx_c = (c <= 0.f) ? 0.f  : 5.f,  st_c = (c <= 0.f) ? 0.f : 3.f;
        float dx_f = (f <= 0.f) ? 0.f  : 5.f,  st_f = (f <= 0.f) ? 2.f : 3.f;
        float dx_e = (e <= 0.f) ? -5.f : 5.f,  st_e = (e <= 0.f) ? 1.f : 3.f;
        float dx_b = (b <= 0.f) ? dx_c : dx_f, st_b = (b <= 0.f) ? st_c : st_f;
        float dx_d = (d <= 0.f) ? dx_e : dx_f, st_d = (d <= 0.f) ? st_e : st_f;
        float dx   = (a <= 0.f) ? dx_b : dx_d, st   = (a <= 0.f) ? st_b : st_d;

        s[1] += dx; s[9] = st;
        s[2] += 5.f; s[3] += 5.f; s[0] += 1.f;
        float dA = s[1] - s[3], dB = s[2] - s[4];
        s[10] = dA * dA + dB * dB;

        // ---- record s[TRAJ_IDX] into the LDS window (cols c0..c0+9) ----
        float v0 = s[10], v1 = s[1], v2 = s[2], v3 = s[3], v4 = s[4];
        float v5 = s[5],  v6 = s[6], v7 = s[7], v8 = s[8], v9 = s[17];
        const int c0 = 28 + 10 * t;
        const int kk = nextb - c0;       // uniform split point
        int off = c0 - wstart;
        if (kk >= 10) {                  // record fits current window
            rec(off + 0, v0); rec(off + 1, v1); rec(off + 2, v2);
            rec(off + 3, v3); rec(off + 4, v4); rec(off + 5, v5);
            rec(off + 6, v6); rec(off + 7, v7); rec(off + 8, v8);
            rec(off + 9, v9);
            if (kk == 10) {              // window exactly full (t = 14)
                flush32(wstart);
                wstart = nextb; nextb += 32;
            }
        } else {                         // record straddles the boundary
            if (kk > 0) rec(off + 0, v0);
            if (kk > 1) rec(off + 1, v1);
            if (kk > 2) rec(off + 2, v2);
            if (kk > 3) rec(off + 3, v3);
            if (kk > 4) rec(off + 4, v4);
            if (kk > 5) rec(off + 5, v5);
            if (kk > 6) rec(off + 6, v6);
            if (kk > 7) rec(off + 7, v7);
            if (kk > 8) rec(off + 8, v8);
            if (kk > 9) rec(off + 9, v9);
            flush32(wstart);
            wstart = nextb; nextb += 32;
            off = c0 - wstart;           // negative; off+j >= 0 for j >= kk
            if (kk <= 0) rec(off + 0, v0);
            if (kk <= 1) rec(off + 1, v1);
            if (kk <= 2) rec(off + 2, v2);
            if (kk <= 3) rec(off + 3, v3);
            if (kk <= 4) rec(off + 4, v4);
            if (kk <= 5) rec(off + 5, v5);
            if (kk <= 6) rec(off + 6, v6);
            if (kk <= 7) rec(off + 7, v7);
            if (kk <= 8) rec(off + 8, v8);
            if (kk <= 9) rec(off + 9, v9);
        }
    }

    // ---- final state, cols 0..17, coalesced via LDS ----
    __syncthreads();
    if (!half) {
        #pragma unroll
        for (int j = 0; j < 18; ++j) lr[j] = s[j];
    }
    __syncthreads();
    #pragma unroll
    for (int j = 0; j < 9; ++j) {
        int flat = tid + 256 * j;                          // 0..2303
        int r = (int)(((unsigned)flat * 58255u) >> 20);    // flat / 18
        int c = flat - r * 18;
        out[(size_t)(R0 + r) * 178 + c] = lds[r * PAD + c];
    }
}

extern "C" void kernel_launch(void* const* d_in, const int* in_sizes, int n_in,
                              void* d_out, int out_size, void* d_ws, size_t ws_size,
                              hipStream_t stream) {
    const float* x   = (const float*)d_in[0];
    const float* c1w = (const float*)d_in[1];
    const float* c1b = (const float*)d_in[2];
    const float* c2w = (const float*)d_in[3];
    const float* c2b = (const float*)d_in[4];
    const float* l1w = (const float*)d_in[5];
    const float* l1b = (const float*)d_in[6];
    const float* l2w = (const float*)d_in[7];
    const float* l2b = (const float*)d_in[8];
    float* out = (float*)d_out;

    Program_4578435138231_kernel<<<kB / RPB, 256, 0, stream>>>(
        x, c1w, c1b, c2w, c2b, l1w, l1b, l2w, l2b, out);
}